// Round 3
// baseline (709.082 us; speedup 1.0000x reference)
//
#include <hip/hip_runtime.h>
#include <hip/hip_bf16.h>

#define NN 50000
#define EE 800000
#define IN_DIM 64
#define DS_DIM 32
#define HOUT_DIM 64

typedef __attribute__((ext_vector_type(8))) short bf16x8;
typedef __attribute__((ext_vector_type(4))) float f32x4;

__device__ __forceinline__ float fast_tanh(float x) {
    float xc = fminf(fmaxf(x, -15.f), 15.f);
    float e2 = __expf(2.f * xc);
    return __fdividef(e2 - 1.f, e2 + 1.f);
}

__device__ __forceinline__ void atomAddF(float* p, float v) {
#if defined(__AMDGCN__)
    unsafeAtomicAdd(p, v);
#else
    atomicAdd(p, v);
#endif
}

__device__ __forceinline__ short f2b(float f) {
    union { __hip_bfloat16 h; short s; } u;
    u.h = __float2bfloat16(f);
    return u.s;
}

// K1: per-node encoders. thread = (node, f) with f in [0,128).
__global__ void k1_encoders(const float* __restrict__ x,
                            const float* __restrict__ WencK, const float* __restrict__ bencK,
                            const float* __restrict__ WencP1, const float* __restrict__ bencP1,
                            const float* __restrict__ WencP2, const float* __restrict__ bencP2,
                            const float* __restrict__ WD, const float* __restrict__ bD,
                            float* __restrict__ hK, float* __restrict__ h1,
                            float* __restrict__ h2, float* __restrict__ DxU) {
    int tid = blockIdx.x * blockDim.x + threadIdx.x;
    int n = tid >> 7;
    int f = tid & 127;
    if (n >= NN) return;
    const float* xr = x + (size_t)n * IN_DIM;
    int j = f & 31;
    if (f < 32) {
        float acc = bencK[j];
        #pragma unroll
        for (int k = 0; k < 32; k++) acc = fmaf(xr[32 + k], WencK[k * 32 + j], acc);
        hK[(size_t)n * 32 + j] = acc;
    } else if (f < 64) {
        float acc = bencP1[j];
        #pragma unroll
        for (int k = 0; k < 32; k++) acc = fmaf(xr[k], WencP1[k * 32 + j], acc);
        h1[(size_t)n * 32 + j] = acc;
    } else if (f < 96) {
        float acc = bencP2[j];
        #pragma unroll
        for (int k = 0; k < 32; k++) acc = fmaf(xr[k], WencP2[k * 32 + j], acc);
        h2[(size_t)n * 32 + j] = acc;
    } else {
        float acc = bD[32 + j];
        #pragma unroll
        for (int k = 0; k < 64; k++) acc = fmaf(xr[k], WD[k * 64 + 32 + j], acc);
        DxU[(size_t)n * 32 + j] = acc;
    }
}

// ---- CSR build: histogram -> scan -> rank-scatter ----
__global__ void khist(const int* __restrict__ dst, int* __restrict__ cnt) {
    int e = blockIdx.x * blockDim.x + threadIdx.x;
    if (e < EE) atomicAdd(&cnt[dst[e]], 1);
}

// single-block exclusive scan of cnt[NN] -> rowptr[NN+1]
__global__ void __launch_bounds__(1024) kscan(const int* __restrict__ cnt, int* __restrict__ rowptr) {
    __shared__ int part[1024];
    const int T = 1024;
    const int per = (NN + T - 1) / T;  // 49
    int t = threadIdx.x;
    int lo = t * per; if (lo > NN) lo = NN;
    int hi = lo + per; if (hi > NN) hi = NN;
    int s = 0;
    for (int i = lo; i < hi; i++) s += cnt[i];
    part[t] = s;
    __syncthreads();
    // Hillis-Steele inclusive scan
    for (int off = 1; off < T; off <<= 1) {
        int v = (t >= off) ? part[t - off] : 0;
        __syncthreads();
        part[t] += v;
        __syncthreads();
    }
    int run = (t == 0) ? 0 : part[t - 1];  // exclusive prefix
    for (int i = lo; i < hi; i++) { rowptr[i] = run; run += cnt[i]; }
    if (t == T - 1) rowptr[NN] = run;      // == EE
}

__global__ void krank(const int* __restrict__ src, const int* __restrict__ dst,
                      const int* __restrict__ rowptr, int* __restrict__ fill,
                      int* __restrict__ srcp, int* __restrict__ dstp) {
    int e = blockIdx.x * blockDim.x + threadIdx.x;
    if (e >= EE) return;
    int d = dst[e];
    int r = atomicAdd(&fill[d], 1);
    int pos = rowptr[d] + r;
    srcp[pos] = src[e];
    dstp[pos] = d;
}

// KAGG: gather-based segment sums (replaces atomic k2). One wave per node.
// lanes 0..31 accumulate hK features, lanes 32..63 accumulate DxU features.
__global__ void __launch_bounds__(256) kagg(const int* __restrict__ rowptr, const int* __restrict__ srcp,
                                            const float* __restrict__ hK, const float* __restrict__ DxU,
                                            float* __restrict__ hKagg, float* __restrict__ dagg) {
    int w = (blockIdx.x * blockDim.x + threadIdx.x) >> 6;
    int lane = threadIdx.x & 63;
    if (w >= NN) return;
    int lo = rowptr[w], hi = rowptr[w + 1];
    const float* arr = (lane < 32) ? hK : DxU;
    int f = lane & 31;
    float acc = 0.f;
    for (int p = lo; p < hi; p++) {
        int s = srcp[p];
        acc += arr[(size_t)s * 32 + f];
    }
    if (lane < 32) hKagg[(size_t)w * 32 + f] = acc;
    else           dagg [(size_t)w * 32 + f] = acc;
}

// K3: E_node = mlp3(hK_agg). node-per-thread, fully unrolled f32.
__global__ void k3_node_mlp(const float* __restrict__ hK_agg,
                            const float* __restrict__ WK1, const float* __restrict__ bK1,
                            const float* __restrict__ WK2, const float* __restrict__ bK2,
                            const float* __restrict__ WK3, const float* __restrict__ bK3,
                            float* __restrict__ Enode) {
    int n = blockIdx.x * blockDim.x + threadIdx.x;
    if (n >= NN) return;
    float in[32];
    const float4* iv = reinterpret_cast<const float4*>(hK_agg + (size_t)n * 32);
    #pragma unroll
    for (int i = 0; i < 8; i++) {
        float4 v = iv[i];
        in[4 * i + 0] = v.x; in[4 * i + 1] = v.y; in[4 * i + 2] = v.z; in[4 * i + 3] = v.w;
    }
    float t1[64];
    #pragma unroll
    for (int j = 0; j < 64; j++) t1[j] = bK1[j];
    #pragma unroll
    for (int k = 0; k < 32; k++) {
        float s0 = in[k];
        #pragma unroll
        for (int j = 0; j < 64; j++) t1[j] = fmaf(s0, WK1[k * 64 + j], t1[j]);
    }
    #pragma unroll
    for (int j = 0; j < 64; j++) t1[j] = fast_tanh(t1[j]);
    float t2[64];
    #pragma unroll
    for (int j = 0; j < 64; j++) t2[j] = bK2[j];
    #pragma unroll
    for (int k = 0; k < 64; k++) {
        float s0 = t1[k];
        #pragma unroll
        for (int j = 0; j < 64; j++) t2[j] = fmaf(s0, WK2[k * 64 + j], t2[j]);
    }
    #pragma unroll
    for (int j = 0; j < 64; j++) t2[j] = fmaxf(t2[j], 0.f);
    float t3[64];
    #pragma unroll
    for (int j = 0; j < 64; j++) t3[j] = bK3[j];
    #pragma unroll
    for (int k = 0; k < 64; k++) {
        float s0 = t2[k];
        #pragma unroll
        for (int j = 0; j < 64; j++) t3[j] = fmaf(s0, WK3[k * 64 + j], t3[j]);
    }
    float4* ov = reinterpret_cast<float4*>(Enode + (size_t)n * 64);
    #pragma unroll
    for (int i = 0; i < 16; i++) {
        float4 v; v.x = t3[4 * i + 0]; v.y = t3[4 * i + 1]; v.z = t3[4 * i + 2]; v.w = t3[4 * i + 3];
        ov[i] = v;
    }
}

// K4 (MFMA, sorted edges): edge MLP on matrix cores over dst-sorted edge list.
// D frag (m89-verified): col=lane&15, row=(lane>>4)*4+reg. Since edges are
// sorted by dst, dst is uniform across each g-group's 16 lanes, so runs of
// equal dst inside a lane's 4 rows are merged in-register before the atomic.
__global__ void __launch_bounds__(256) k4_mfma(
    const int* __restrict__ srcp, const int* __restrict__ dstp,
    const float* __restrict__ h1, const float* __restrict__ h2,
    const float* __restrict__ Enode, float* __restrict__ Enew,
    const float* __restrict__ WU1, const float* __restrict__ bU1,
    const float* __restrict__ WU2, const float* __restrict__ bU2,
    const float* __restrict__ WU3, const float* __restrict__ bU3)
{
    __shared__ float xpose[4][16 * 68];
    const int wid  = threadIdx.x >> 6;
    const int lane = threadIdx.x & 63;
    const int g = lane >> 4;   // k-group 0..3
    const int r = lane & 15;   // A-row / D-col selector
    float* xp = xpose[wid];

    // ---- loop-invariant weight fragments (VGPR-resident) ----
    bf16x8 b1[4];            // W1: [32][64]
    #pragma unroll
    for (int nt = 0; nt < 4; nt++) {
        #pragma unroll
        for (int i = 0; i < 8; i++)
            b1[nt][i] = f2b(WU1[(g * 8 + i) * 64 + nt * 16 + r]);
    }
    bf16x8 b2[2][4], b3[2][4];  // W2,W3: [64][64], 2 K-chunks
    #pragma unroll
    for (int c = 0; c < 2; c++) {
        #pragma unroll
        for (int nt = 0; nt < 4; nt++) {
            #pragma unroll
            for (int i = 0; i < 8; i++) {
                b2[c][nt][i] = f2b(WU2[(c * 32 + g * 8 + i) * 64 + nt * 16 + r]);
                b3[c][nt][i] = f2b(WU3[(c * 32 + g * 8 + i) * 64 + nt * 16 + r]);
            }
        }
    }
    float bias1[4], bias2[4], bias3[4];
    #pragma unroll
    for (int nt = 0; nt < 4; nt++) {
        bias1[nt] = bU1[nt * 16 + r];
        bias2[nt] = bU2[nt * 16 + r];
        bias3[nt] = bU3[nt * 16 + r];
    }

    const int ntiles = EE / 16;                 // 50000, exact
    const int wave = blockIdx.x * 4 + wid;
    const int nw = gridDim.x * 4;
    const f32x4 zero = {0.f, 0.f, 0.f, 0.f};

    for (int tile = wave; tile < ntiles; tile += nw) {
        const int e0 = tile * 16;
        const int s_me = srcp[e0 + r];
        const int d_me = dstp[e0 + r];

        // ---- layer 1: A = e_out[16 x 32] built straight from gathers ----
        bf16x8 a;
        {
            const float* p1 = h1 + (size_t)s_me * 32 + g * 8;
            const float* p2 = h2 + (size_t)d_me * 32 + g * 8;
            float4 x0 = *reinterpret_cast<const float4*>(p1);
            float4 x1 = *reinterpret_cast<const float4*>(p1 + 4);
            float4 y0 = *reinterpret_cast<const float4*>(p2);
            float4 y1 = *reinterpret_cast<const float4*>(p2 + 4);
            a[0] = f2b(x0.x + y0.x); a[1] = f2b(x0.y + y0.y);
            a[2] = f2b(x0.z + y0.z); a[3] = f2b(x0.w + y0.w);
            a[4] = f2b(x1.x + y1.x); a[5] = f2b(x1.y + y1.y);
            a[6] = f2b(x1.z + y1.z); a[7] = f2b(x1.w + y1.w);
        }
        f32x4 acc[4];
        #pragma unroll
        for (int nt = 0; nt < 4; nt++)
            acc[nt] = __builtin_amdgcn_mfma_f32_16x16x32_bf16(a, b1[nt], zero, 0, 0, 0);

        // tanh + bias, write transposed: row=edge=(g*4+q), col=nt*16+r
        #pragma unroll
        for (int nt = 0; nt < 4; nt++) {
            #pragma unroll
            for (int q = 0; q < 4; q++)
                xp[(g * 4 + q) * 68 + nt * 16 + r] = fast_tanh(acc[nt][q] + bias1[nt]);
        }

        // ---- layer 2 ----
        f32x4 acc2[4] = {zero, zero, zero, zero};
        #pragma unroll
        for (int c = 0; c < 2; c++) {
            const float* row = xp + r * 68 + c * 32 + g * 8;
            bf16x8 af;
            #pragma unroll
            for (int i = 0; i < 8; i++) af[i] = f2b(row[i]);
            #pragma unroll
            for (int nt = 0; nt < 4; nt++)
                acc2[nt] = __builtin_amdgcn_mfma_f32_16x16x32_bf16(af, b2[c][nt], acc2[nt], 0, 0, 0);
        }
        #pragma unroll
        for (int nt = 0; nt < 4; nt++) {
            #pragma unroll
            for (int q = 0; q < 4; q++)
                xp[(g * 4 + q) * 68 + nt * 16 + r] = fmaxf(acc2[nt][q] + bias2[nt], 0.f);
        }

        // ---- layer 3 ----
        f32x4 acc3[4] = {zero, zero, zero, zero};
        #pragma unroll
        for (int c = 0; c < 2; c++) {
            const float* row = xp + r * 68 + c * 32 + g * 8;
            bf16x8 af;
            #pragma unroll
            for (int i = 0; i < 8; i++) af[i] = f2b(row[i]);
            #pragma unroll
            for (int nt = 0; nt < 4; nt++)
                acc3[nt] = __builtin_amdgcn_mfma_f32_16x16x32_bf16(af, b3[c][nt], acc3[nt], 0, 0, 0);
        }

        // ---- multiply by Enode[src], compact equal-dst runs, atomic scatter ----
        float val[4][4];   // [nt][q]
        int dq[4];
        #pragma unroll
        for (int q = 0; q < 4; q++) {
            const int er = g * 4 + q;
            const int ss = __shfl(s_me, er);
            dq[q] = __shfl(d_me, er);
            const float* en = Enode + (size_t)ss * 64 + r;
            #pragma unroll
            for (int nt = 0; nt < 4; nt++)
                val[nt][q] = (acc3[nt][q] + bias3[nt]) * en[nt * 16];
        }
        bool keep[4];
        keep[0] = true;
        #pragma unroll
        for (int q = 1; q < 4; q++) keep[q] = (dq[q] != dq[q - 1]);
        #pragma unroll
        for (int q = 3; q >= 1; q--) {
            if (!keep[q]) {
                #pragma unroll
                for (int nt = 0; nt < 4; nt++) val[nt][q - 1] += val[nt][q];
            }
        }
        #pragma unroll
        for (int q = 0; q < 4; q++) {
            if (keep[q]) {
                float* ew = Enew + (size_t)dq[q] * 64 + r;
                #pragma unroll
                for (int nt = 0; nt < 4; nt++) atomAddF(ew + nt * 16, val[nt][q]);
            }
        }
    }
}

// K5: dH = E_new @ WH + bH ; out[:, :32] = dH[:,32:], out[:,32:] = -dH[:,:32] - d_agg
__global__ void k5_out(const float* __restrict__ Enew, const float* __restrict__ d_agg,
                       const float* __restrict__ WH, const float* __restrict__ bH,
                       float* __restrict__ out) {
    int tid = blockIdx.x * blockDim.x + threadIdx.x;
    int n = tid >> 6;
    int j = tid & 63;
    if (n >= NN) return;
    const float* er = Enew + (size_t)n * 64;
    int jj = (j < 32) ? (j + 32) : (j - 32);
    float acc = bH[jj];
    #pragma unroll
    for (int k = 0; k < 64; k++) acc = fmaf(er[k], WH[k * 64 + jj], acc);
    float val;
    if (j < 32) {
        val = acc;
    } else {
        val = -acc - d_agg[(size_t)n * 32 + (j - 32)];
    }
    out[tid] = val;
}

extern "C" void kernel_launch(void* const* d_in, const int* in_sizes, int n_in,
                              void* d_out, int out_size, void* d_ws, size_t ws_size,
                              hipStream_t stream) {
    const float* x      = (const float*)d_in[0];
    const int*   src    = (const int*)d_in[1];
    const int*   dst    = (const int*)d_in[2];
    const float* WencK  = (const float*)d_in[3];
    const float* bencK  = (const float*)d_in[4];
    const float* WencP1 = (const float*)d_in[5];
    const float* bencP1 = (const float*)d_in[6];
    const float* WencP2 = (const float*)d_in[7];
    const float* bencP2 = (const float*)d_in[8];
    const float* WK1    = (const float*)d_in[9];
    const float* bK1    = (const float*)d_in[10];
    const float* WK2    = (const float*)d_in[11];
    const float* bK2    = (const float*)d_in[12];
    const float* WK3    = (const float*)d_in[13];
    const float* bK3    = (const float*)d_in[14];
    const float* WU1    = (const float*)d_in[15];
    const float* bU1    = (const float*)d_in[16];
    const float* WU2    = (const float*)d_in[17];
    const float* bU2    = (const float*)d_in[18];
    const float* WU3    = (const float*)d_in[19];
    const float* bU3    = (const float*)d_in[20];
    const float* WH     = (const float*)d_in[21];
    const float* bH     = (const float*)d_in[22];
    const float* WD     = (const float*)d_in[23];
    const float* bD     = (const float*)d_in[24];
    float* out = (float*)d_out;

    // ---- workspace layout (total 58.2 MB <= proven-available 64 MB) ----
    float* ws = (float*)d_ws;
    float* h1     = ws;                          // NN*32
    float* h2     = h1 + (size_t)NN * 32;        // NN*32
    float* hK     = h2 + (size_t)NN * 32;        // NN*32  (dead after kagg)
    float* DxU    = hK + (size_t)NN * 32;        // NN*32  (dead after kagg)
    float* Enew   = hK;                          // NN*64, ALIASES hK+DxU
    float* hKagg  = DxU + (size_t)NN * 32;       // NN*32  (dead after k3)
    float* dagg   = hKagg + (size_t)NN * 32;     // NN*32  (live to k5)
    float* Enode  = dagg + (size_t)NN * 32;      // NN*64
    int*   cnt    = (int*)(Enode + (size_t)NN * 64);  // NN
    int*   fill   = cnt + NN;                    // NN
    int*   rowptr = fill + NN;                   // NN+1
    int*   srcp   = rowptr + NN + 1;             // EE
    int*   dstp   = srcp + EE;                   // EE
    size_t need = ((size_t)NN * 32 * 6 + (size_t)NN * 64) * sizeof(float)
                + ((size_t)NN * 3 + 1 + (size_t)EE * 2) * sizeof(int);
    if (ws_size < need) return;

    // zero histogram + rank counters (contiguous cnt|fill)
    hipMemsetAsync(cnt, 0, (size_t)2 * NN * sizeof(int), stream);

    k1_encoders<<<(NN * 128 + 255) / 256, 256, 0, stream>>>(
        x, WencK, bencK, WencP1, bencP1, WencP2, bencP2, WD, bD, hK, h1, h2, DxU);
    khist<<<(EE + 255) / 256, 256, 0, stream>>>(dst, cnt);
    kscan<<<1, 1024, 0, stream>>>(cnt, rowptr);
    krank<<<(EE + 255) / 256, 256, 0, stream>>>(src, dst, rowptr, fill, srcp, dstp);
    kagg<<<(NN * 64 + 255) / 256, 256, 0, stream>>>(rowptr, srcp, hK, DxU, hKagg, dagg);
    // hK/DxU now dead -> safe to zero the aliasing Enew
    hipMemsetAsync(Enew, 0, (size_t)NN * 64 * sizeof(float), stream);
    k3_node_mlp<<<(NN + 63) / 64, 64, 0, stream>>>(hKagg, WK1, bK1, WK2, bK2, WK3, bK3, Enode);
    k4_mfma<<<2048, 256, 0, stream>>>(srcp, dstp, h1, h2, Enode, Enew, WU1, bU1, WU2, bU2, WU3, bU3);
    k5_out<<<(NN * 64 + 255) / 256, 256, 0, stream>>>(Enew, dagg, WH, bH, out);
}

// Round 4
// 586.489 us; speedup vs baseline: 1.2090x; 1.2090x over previous
//
#include <hip/hip_runtime.h>
#include <hip/hip_bf16.h>

#define NN 50000
#define EE 800000
#define IN_DIM 64
#define DS_DIM 32
#define HOUT_DIM 64

// k4 chunking: 5000 waves x 160 edges; row r owns stream of C=10 edges.
#define K4_WAVES 5000
#define K4_EPW   160
#define K4_C     10

typedef __attribute__((ext_vector_type(8))) short bf16x8;
typedef __attribute__((ext_vector_type(4))) float f32x4;

__device__ __forceinline__ float fast_tanh(float x) {
    float xc = fminf(fmaxf(x, -15.f), 15.f);
    float e2 = __expf(2.f * xc);
    return __fdividef(e2 - 1.f, e2 + 1.f);
}

__device__ __forceinline__ void atomAddF(float* p, float v) {
#if defined(__AMDGCN__)
    unsafeAtomicAdd(p, v);
#else
    atomicAdd(p, v);
#endif
}

__device__ __forceinline__ short f2b(float f) {
    union { __hip_bfloat16 h; short s; } u;
    u.h = __float2bfloat16(f);
    return u.s;
}
__device__ __forceinline__ float b2f(unsigned short u) {
    return __uint_as_float(((unsigned int)u) << 16);
}
__device__ __forceinline__ unsigned int pack2(float lo, float hi) {
    return (unsigned int)(unsigned short)f2b(lo) | (((unsigned int)(unsigned short)f2b(hi)) << 16);
}

// K1b: h1 = q@WencP1+b, h2 = q@WencP2+b, stored bf16. thread = (node, j<32).
__global__ void k1b(const float* __restrict__ x,
                    const float* __restrict__ WencP1, const float* __restrict__ bencP1,
                    const float* __restrict__ WencP2, const float* __restrict__ bencP2,
                    __hip_bfloat16* __restrict__ h1b, __hip_bfloat16* __restrict__ h2b) {
    int tid = blockIdx.x * blockDim.x + threadIdx.x;
    int n = tid >> 5;
    int j = tid & 31;
    if (n >= NN) return;
    const float* xr = x + (size_t)n * IN_DIM;
    float a1 = bencP1[j], a2 = bencP2[j];
    #pragma unroll
    for (int k = 0; k < 32; k++) {
        float q = xr[k];
        a1 = fmaf(q, WencP1[k * 32 + j], a1);
        a2 = fmaf(q, WencP2[k * 32 + j], a2);
    }
    union { __hip_bfloat16 h; short s; } u1, u2;
    u1.s = f2b(a1); u2.s = f2b(a2);
    h1b[(size_t)n * 32 + j] = u1.h;
    h2b[(size_t)n * 32 + j] = u2.h;
}

// KHIST: per-dst histogram + per-edge rank (atomicAdd return).
__global__ void khist(const int* __restrict__ dst, int* __restrict__ cnt, int* __restrict__ rank) {
    int e = blockIdx.x * blockDim.x + threadIdx.x;
    if (e < EE) rank[e] = atomicAdd(&cnt[dst[e]], 1);
}

// single-block exclusive scan of cnt[NN] -> rowptr[NN+1]
__global__ void __launch_bounds__(1024) kscan(const int* __restrict__ cnt, int* __restrict__ rowptr) {
    __shared__ int part[1024];
    const int T = 1024;
    const int per = (NN + T - 1) / T;
    int t = threadIdx.x;
    int lo = t * per; if (lo > NN) lo = NN;
    int hi = lo + per; if (hi > NN) hi = NN;
    int s = 0;
    for (int i = lo; i < hi; i++) s += cnt[i];
    part[t] = s;
    __syncthreads();
    for (int off = 1; off < T; off <<= 1) {
        int v = (t >= off) ? part[t - off] : 0;
        __syncthreads();
        part[t] += v;
        __syncthreads();
    }
    int run = (t == 0) ? 0 : part[t - 1];
    for (int i = lo; i < hi; i++) { rowptr[i] = run; run += cnt[i]; }
    if (t == T - 1) rowptr[NN] = run;
}

// KSCATTER: place edges into dst-sorted order using precomputed rank.
__global__ void kscatter(const int* __restrict__ src, const int* __restrict__ dst,
                         const int* __restrict__ rowptr, const int* __restrict__ rank,
                         int* __restrict__ srcp, int* __restrict__ dstp) {
    int e = blockIdx.x * blockDim.x + threadIdx.x;
    if (e >= EE) return;
    int d = dst[e];
    int pos = rowptr[d] + rank[e];
    srcp[pos] = src[e];
    dstp[pos] = d;
}

// KXAGG: xagg[n] = sum of x rows over in-edges (CSR gather). wave per node.
__global__ void __launch_bounds__(256) kxagg(const int* __restrict__ rowptr, const int* __restrict__ srcp,
                                             const float* __restrict__ x, float* __restrict__ xagg) {
    int w = (blockIdx.x * blockDim.x + threadIdx.x) >> 6;
    int lane = threadIdx.x & 63;
    if (w >= NN) return;
    int lo = rowptr[w], hi = rowptr[w + 1];
    float acc = 0.f;
    int p = lo;
    for (; p + 3 < hi; p += 4) {
        int s0 = srcp[p], s1 = srcp[p + 1], s2 = srcp[p + 2], s3 = srcp[p + 3];
        float v0 = x[(size_t)s0 * 64 + lane];
        float v1 = x[(size_t)s1 * 64 + lane];
        float v2 = x[(size_t)s2 * 64 + lane];
        float v3 = x[(size_t)s3 * 64 + lane];
        acc += (v0 + v1) + (v2 + v3);
    }
    for (; p < hi; p++) acc += x[(size_t)srcp[p] * 64 + lane];
    xagg[(size_t)w * 64 + lane] = acc;
}

// K3F: fused linear-agg encoders + node MLP. thread per node.
//   hKagg = xagg[:,32:]@WencK + cnt*bencK ;  dagg = xagg@WD[:,32:] + cnt*bD[32:]
//   Enode = mlp3(hKagg) stored bf16.
__global__ void k3f(const float* __restrict__ xagg, const int* __restrict__ cnt,
                    const float* __restrict__ WencK, const float* __restrict__ bencK,
                    const float* __restrict__ WD, const float* __restrict__ bD,
                    const float* __restrict__ WK1, const float* __restrict__ bK1,
                    const float* __restrict__ WK2, const float* __restrict__ bK2,
                    const float* __restrict__ WK3, const float* __restrict__ bK3,
                    float* __restrict__ dagg, __hip_bfloat16* __restrict__ EnodeB) {
    int n = blockIdx.x * blockDim.x + threadIdx.x;
    if (n >= NN) return;
    float xa[64];
    const float4* iv = reinterpret_cast<const float4*>(xagg + (size_t)n * 64);
    #pragma unroll
    for (int i = 0; i < 16; i++) {
        float4 v = iv[i];
        xa[4 * i + 0] = v.x; xa[4 * i + 1] = v.y; xa[4 * i + 2] = v.z; xa[4 * i + 3] = v.w;
    }
    float c = (float)cnt[n];
    // dagg
    {
        float dg[32];
        #pragma unroll
        for (int j = 0; j < 32; j++) dg[j] = c * bD[32 + j];
        #pragma unroll
        for (int k = 0; k < 64; k++) {
            float s0 = xa[k];
            #pragma unroll
            for (int j = 0; j < 32; j++) dg[j] = fmaf(s0, WD[k * 64 + 32 + j], dg[j]);
        }
        float4* ov = reinterpret_cast<float4*>(dagg + (size_t)n * 32);
        #pragma unroll
        for (int i = 0; i < 8; i++) {
            float4 v; v.x = dg[4 * i]; v.y = dg[4 * i + 1]; v.z = dg[4 * i + 2]; v.w = dg[4 * i + 3];
            ov[i] = v;
        }
    }
    // hKagg
    float hk[32];
    #pragma unroll
    for (int j = 0; j < 32; j++) hk[j] = c * bencK[j];
    #pragma unroll
    for (int k = 0; k < 32; k++) {
        float s0 = xa[32 + k];
        #pragma unroll
        for (int j = 0; j < 32; j++) hk[j] = fmaf(s0, WencK[k * 32 + j], hk[j]);
    }
    // MLP
    float t1[64];
    #pragma unroll
    for (int j = 0; j < 64; j++) t1[j] = bK1[j];
    #pragma unroll
    for (int k = 0; k < 32; k++) {
        float s0 = hk[k];
        #pragma unroll
        for (int j = 0; j < 64; j++) t1[j] = fmaf(s0, WK1[k * 64 + j], t1[j]);
    }
    #pragma unroll
    for (int j = 0; j < 64; j++) t1[j] = fast_tanh(t1[j]);
    float t2[64];
    #pragma unroll
    for (int j = 0; j < 64; j++) t2[j] = bK2[j];
    #pragma unroll
    for (int k = 0; k < 64; k++) {
        float s0 = t1[k];
        #pragma unroll
        for (int j = 0; j < 64; j++) t2[j] = fmaf(s0, WK2[k * 64 + j], t2[j]);
    }
    #pragma unroll
    for (int j = 0; j < 64; j++) t2[j] = fmaxf(t2[j], 0.f);
    float t3[64];
    #pragma unroll
    for (int j = 0; j < 64; j++) t3[j] = bK3[j];
    #pragma unroll
    for (int k = 0; k < 64; k++) {
        float s0 = t2[k];
        #pragma unroll
        for (int j = 0; j < 64; j++) t3[j] = fmaf(s0, WK3[k * 64 + j], t3[j]);
    }
    uint4* ob = reinterpret_cast<uint4*>(EnodeB + (size_t)n * 64);
    #pragma unroll
    for (int i = 0; i < 8; i++) {
        uint4 v;
        v.x = pack2(t3[8 * i + 0], t3[8 * i + 1]);
        v.y = pack2(t3[8 * i + 2], t3[8 * i + 3]);
        v.z = pack2(t3[8 * i + 4], t3[8 * i + 5]);
        v.w = pack2(t3[8 * i + 6], t3[8 * i + 7]);
        ob[i] = v;
    }
}

// K4 v3 (MFMA, row-stream chunks, carry-merged scatter).
// Wave owns 160 consecutive sorted edges; MFMA row r <-> edge base + r*10 + t.
// Per-(lane,q) carry merges equal-dst runs across tiles -> one atomic row-write per run.
__global__ void __launch_bounds__(256) k4_mfma(
    const int* __restrict__ srcp, const int* __restrict__ dstp,
    const __hip_bfloat16* __restrict__ h1b, const __hip_bfloat16* __restrict__ h2b,
    const __hip_bfloat16* __restrict__ EnodeB, float* __restrict__ Enew,
    const float* __restrict__ WU1, const float* __restrict__ bU1,
    const float* __restrict__ WU2, const float* __restrict__ bU2,
    const float* __restrict__ WU3, const float* __restrict__ bU3)
{
    __shared__ float xpose[4][16 * 68];
    const int wid  = threadIdx.x >> 6;
    const int lane = threadIdx.x & 63;
    const int g = lane >> 4;   // k-group 0..3
    const int r = lane & 15;   // A-row / D-col selector
    float* xp = xpose[wid];

    // loop-invariant weight fragments
    bf16x8 b1[4];
    #pragma unroll
    for (int nt = 0; nt < 4; nt++) {
        #pragma unroll
        for (int i = 0; i < 8; i++)
            b1[nt][i] = f2b(WU1[(g * 8 + i) * 64 + nt * 16 + r]);
    }
    bf16x8 b2[2][4], b3[2][4];
    #pragma unroll
    for (int c = 0; c < 2; c++) {
        #pragma unroll
        for (int nt = 0; nt < 4; nt++) {
            #pragma unroll
            for (int i = 0; i < 8; i++) {
                b2[c][nt][i] = f2b(WU2[(c * 32 + g * 8 + i) * 64 + nt * 16 + r]);
                b3[c][nt][i] = f2b(WU3[(c * 32 + g * 8 + i) * 64 + nt * 16 + r]);
            }
        }
    }
    float bias1[4], bias2[4], bias3[4];
    #pragma unroll
    for (int nt = 0; nt < 4; nt++) {
        bias1[nt] = bU1[nt * 16 + r];
        bias2[nt] = bU2[nt * 16 + r];
        bias3[nt] = bU3[nt * 16 + r];
    }

    const int wave = blockIdx.x * 4 + wid;     // [0, K4_WAVES)
    const int base = wave * K4_EPW;
    const f32x4 zero = {0.f, 0.f, 0.f, 0.f};

    int   cd[4] = {-1, -1, -1, -1};            // carry dst per q
    float cv0[4] = {0, 0, 0, 0}, cv1[4] = {0, 0, 0, 0},
          cv2[4] = {0, 0, 0, 0}, cv3[4] = {0, 0, 0, 0};   // carry val [nt][q]

    for (int t = 0; t < K4_C; t++) {
        const int e_r = base + r * K4_C + t;   // edge of MFMA row r
        const int s_me = srcp[e_r];
        const int d_me = dstp[e_r];

        // layer 1 A-fragment: row r, k = g*8 + i ; bf16 gathers
        bf16x8 a;
        {
            union { uint4 v; unsigned int u[4]; } u1, u2;
            u1.v = *reinterpret_cast<const uint4*>(h1b + (size_t)s_me * 32 + g * 8);
            u2.v = *reinterpret_cast<const uint4*>(h2b + (size_t)d_me * 32 + g * 8);
            #pragma unroll
            for (int w = 0; w < 4; w++) {
                float lo = b2f((unsigned short)(u1.u[w] & 0xffff)) + b2f((unsigned short)(u2.u[w] & 0xffff));
                float hi = b2f((unsigned short)(u1.u[w] >> 16))    + b2f((unsigned short)(u2.u[w] >> 16));
                a[2 * w]     = f2b(lo);
                a[2 * w + 1] = f2b(hi);
            }
        }
        f32x4 acc[4];
        #pragma unroll
        for (int nt = 0; nt < 4; nt++)
            acc[nt] = __builtin_amdgcn_mfma_f32_16x16x32_bf16(a, b1[nt], zero, 0, 0, 0);

        #pragma unroll
        for (int nt = 0; nt < 4; nt++) {
            #pragma unroll
            for (int q = 0; q < 4; q++)
                xp[(g * 4 + q) * 68 + nt * 16 + r] = fast_tanh(acc[nt][q] + bias1[nt]);
        }

        f32x4 acc2[4] = {zero, zero, zero, zero};
        #pragma unroll
        for (int c = 0; c < 2; c++) {
            const float* row = xp + r * 68 + c * 32 + g * 8;
            bf16x8 af;
            #pragma unroll
            for (int i = 0; i < 8; i++) af[i] = f2b(row[i]);
            #pragma unroll
            for (int nt = 0; nt < 4; nt++)
                acc2[nt] = __builtin_amdgcn_mfma_f32_16x16x32_bf16(af, b2[c][nt], acc2[nt], 0, 0, 0);
        }
        #pragma unroll
        for (int nt = 0; nt < 4; nt++) {
            #pragma unroll
            for (int q = 0; q < 4; q++)
                xp[(g * 4 + q) * 68 + nt * 16 + r] = fmaxf(acc2[nt][q] + bias2[nt], 0.f);
        }

        f32x4 acc3[4] = {zero, zero, zero, zero};
        #pragma unroll
        for (int c = 0; c < 2; c++) {
            const float* row = xp + r * 68 + c * 32 + g * 8;
            bf16x8 af;
            #pragma unroll
            for (int i = 0; i < 8; i++) af[i] = f2b(row[i]);
            #pragma unroll
            for (int nt = 0; nt < 4; nt++)
                acc3[nt] = __builtin_amdgcn_mfma_f32_16x16x32_bf16(af, b3[c][nt], acc3[nt], 0, 0, 0);
        }

        // multiply by Enode[src], carry-merge per (lane,q), atomic flush on dst change
        #pragma unroll
        for (int q = 0; q < 4; q++) {
            const int er = g * 4 + q;
            const int ssv = __shfl(s_me, er);
            const int dqv = __shfl(d_me, er);
            const unsigned short* enp = reinterpret_cast<const unsigned short*>(EnodeB) + (size_t)ssv * 64 + r;
            float v0 = (acc3[0][q] + bias3[0]) * b2f(enp[0]);
            float v1 = (acc3[1][q] + bias3[1]) * b2f(enp[16]);
            float v2 = (acc3[2][q] + bias3[2]) * b2f(enp[32]);
            float v3 = (acc3[3][q] + bias3[3]) * b2f(enp[48]);
            if (dqv == cd[q]) {
                cv0[q] += v0; cv1[q] += v1; cv2[q] += v2; cv3[q] += v3;
            } else {
                if (cd[q] >= 0) {
                    float* ew = Enew + (size_t)cd[q] * 64 + r;
                    atomAddF(ew,      cv0[q]);
                    atomAddF(ew + 16, cv1[q]);
                    atomAddF(ew + 32, cv2[q]);
                    atomAddF(ew + 48, cv3[q]);
                }
                cd[q] = dqv;
                cv0[q] = v0; cv1[q] = v1; cv2[q] = v2; cv3[q] = v3;
            }
        }
    }
    // final flush
    #pragma unroll
    for (int q = 0; q < 4; q++) {
        if (cd[q] >= 0) {
            float* ew = Enew + (size_t)cd[q] * 64 + r;
            atomAddF(ew,      cv0[q]);
            atomAddF(ew + 16, cv1[q]);
            atomAddF(ew + 32, cv2[q]);
            atomAddF(ew + 48, cv3[q]);
        }
    }
}

// K5: dH = E_new @ WH + bH ; out = [dH[:,32:], -dH[:,:32] - dagg]
__global__ void k5_out(const float* __restrict__ Enew, const float* __restrict__ dagg,
                       const float* __restrict__ WH, const float* __restrict__ bH,
                       float* __restrict__ out) {
    int tid = blockIdx.x * blockDim.x + threadIdx.x;
    int n = tid >> 6;
    int j = tid & 63;
    if (n >= NN) return;
    const float* er = Enew + (size_t)n * 64;
    int jj = (j < 32) ? (j + 32) : (j - 32);
    float acc = bH[jj];
    #pragma unroll
    for (int k = 0; k < 64; k++) acc = fmaf(er[k], WH[k * 64 + jj], acc);
    float val;
    if (j < 32) val = acc;
    else        val = -acc - dagg[(size_t)n * 32 + (j - 32)];
    out[tid] = val;
}

extern "C" void kernel_launch(void* const* d_in, const int* in_sizes, int n_in,
                              void* d_out, int out_size, void* d_ws, size_t ws_size,
                              hipStream_t stream) {
    const float* x      = (const float*)d_in[0];
    const int*   src    = (const int*)d_in[1];
    const int*   dst    = (const int*)d_in[2];
    const float* WencK  = (const float*)d_in[3];
    const float* bencK  = (const float*)d_in[4];
    const float* WencP1 = (const float*)d_in[5];
    const float* bencP1 = (const float*)d_in[6];
    const float* WencP2 = (const float*)d_in[7];
    const float* bencP2 = (const float*)d_in[8];
    const float* WK1    = (const float*)d_in[9];
    const float* bK1    = (const float*)d_in[10];
    const float* WK2    = (const float*)d_in[11];
    const float* bK2    = (const float*)d_in[12];
    const float* WK3    = (const float*)d_in[13];
    const float* bK3    = (const float*)d_in[14];
    const float* WU1    = (const float*)d_in[15];
    const float* bU1    = (const float*)d_in[16];
    const float* WU2    = (const float*)d_in[17];
    const float* bU2    = (const float*)d_in[18];
    const float* WU3    = (const float*)d_in[19];
    const float* bU3    = (const float*)d_in[20];
    const float* WH     = (const float*)d_in[21];
    const float* bH     = (const float*)d_in[22];
    const float* WD     = (const float*)d_in[23];
    const float* bD     = (const float*)d_in[24];
    float* out = (float*)d_out;

    // ---- workspace layout ----
    float* Enew = (float*)d_ws;                                  // NN*64 f32
    float* xagg = Enew + (size_t)NN * 64;                        // NN*64 f32
    float* dagg = xagg + (size_t)NN * 64;                        // NN*32 f32
    __hip_bfloat16* h1b    = (__hip_bfloat16*)(dagg + (size_t)NN * 32);  // NN*32 bf16
    __hip_bfloat16* h2b    = h1b + (size_t)NN * 32;              // NN*32 bf16
    __hip_bfloat16* EnodeB = h2b + (size_t)NN * 32;              // NN*64 bf16
    int* cnt    = (int*)(EnodeB + (size_t)NN * 64);              // NN
    int* rowptr = cnt + NN;                                      // NN+1
    int* rank   = rowptr + NN + 1;                               // EE
    int* srcp   = rank + EE;                                     // EE
    int* dstp   = srcp + EE;                                     // EE
    size_t need = (size_t)NN * 160 * 4 + (size_t)NN * 128 * 2
                + ((size_t)NN * 2 + 1 + (size_t)EE * 3) * 4;
    if (ws_size < need) return;

    hipMemsetAsync(cnt, 0, (size_t)NN * sizeof(int), stream);
    hipMemsetAsync(Enew, 0, (size_t)NN * 64 * sizeof(float), stream);

    khist<<<(EE + 255) / 256, 256, 0, stream>>>(dst, cnt, rank);
    kscan<<<1, 1024, 0, stream>>>(cnt, rowptr);
    kscatter<<<(EE + 255) / 256, 256, 0, stream>>>(src, dst, rowptr, rank, srcp, dstp);
    k1b<<<(NN * 32 + 255) / 256, 256, 0, stream>>>(x, WencP1, bencP1, WencP2, bencP2, h1b, h2b);
    kxagg<<<(NN * 64 + 255) / 256, 256, 0, stream>>>(rowptr, srcp, x, xagg);
    k3f<<<(NN + 255) / 256, 256, 0, stream>>>(xagg, cnt, WencK, bencK, WD, bD,
                                              WK1, bK1, WK2, bK2, WK3, bK3, dagg, EnodeB);
    k4_mfma<<<K4_WAVES / 4, 256, 0, stream>>>(srcp, dstp, h1b, h2b, EnodeB, Enew,
                                              WU1, bU1, WU2, bU2, WU3, bU3);
    k5_out<<<(NN * 64 + 255) / 256, 256, 0, stream>>>(Enew, dagg, WH, bH, out);
}

// Round 5
// 456.663 us; speedup vs baseline: 1.5527x; 1.2843x over previous
//
#include <hip/hip_runtime.h>
#include <hip/hip_bf16.h>

#define NN 50000
#define EE 800000
#define IN_DIM 64
#define DS_DIM 32
#define HOUT_DIM 64

// k4 chunking: 5000 waves x 160 edges; row r owns stream of C=10 edges.
#define K4_WAVES 5000
#define K4_EPW   160
#define K4_C     10

typedef __attribute__((ext_vector_type(8))) short bf16x8;
typedef __attribute__((ext_vector_type(4))) float f32x4;

__device__ __forceinline__ float fast_tanh(float x) {
    float xc = fminf(fmaxf(x, -15.f), 15.f);
    float e2 = __expf(2.f * xc);
    return __fdividef(e2 - 1.f, e2 + 1.f);
}

__device__ __forceinline__ void atomAddF(float* p, float v) {
#if defined(__AMDGCN__)
    unsafeAtomicAdd(p, v);
#else
    atomicAdd(p, v);
#endif
}

__device__ __forceinline__ short f2b(float f) {
    union { __hip_bfloat16 h; short s; } u;
    u.h = __float2bfloat16(f);
    return u.s;
}
__device__ __forceinline__ float b2f(unsigned short u) {
    return __uint_as_float(((unsigned int)u) << 16);
}
__device__ __forceinline__ unsigned int pack2(float lo, float hi) {
    return (unsigned int)(unsigned short)f2b(lo) | (((unsigned int)(unsigned short)f2b(hi)) << 16);
}

// K1b: h1 = q@WencP1+b, h2 = q@WencP2+b, stored bf16. thread = (node, j<32).
__global__ void k1b(const float* __restrict__ x,
                    const float* __restrict__ WencP1, const float* __restrict__ bencP1,
                    const float* __restrict__ WencP2, const float* __restrict__ bencP2,
                    __hip_bfloat16* __restrict__ h1b, __hip_bfloat16* __restrict__ h2b) {
    int tid = blockIdx.x * blockDim.x + threadIdx.x;
    int n = tid >> 5;
    int j = tid & 31;
    if (n >= NN) return;
    const float* xr = x + (size_t)n * IN_DIM;
    float a1 = bencP1[j], a2 = bencP2[j];
    #pragma unroll
    for (int k = 0; k < 32; k++) {
        float q = xr[k];
        a1 = fmaf(q, WencP1[k * 32 + j], a1);
        a2 = fmaf(q, WencP2[k * 32 + j], a2);
    }
    union { __hip_bfloat16 h; short s; } u1, u2;
    u1.s = f2b(a1); u2.s = f2b(a2);
    h1b[(size_t)n * 32 + j] = u1.h;
    h2b[(size_t)n * 32 + j] = u2.h;
}

// KHIST: per-dst histogram + per-edge rank (atomicAdd return).
__global__ void khist(const int* __restrict__ dst, int* __restrict__ cnt, int* __restrict__ rank) {
    int e = blockIdx.x * blockDim.x + threadIdx.x;
    if (e < EE) rank[e] = atomicAdd(&cnt[dst[e]], 1);
}

// single-block exclusive scan of cnt[NN] -> rowptr[NN+1]
__global__ void __launch_bounds__(1024) kscan(const int* __restrict__ cnt, int* __restrict__ rowptr) {
    __shared__ int part[1024];
    const int T = 1024;
    const int per = (NN + T - 1) / T;
    int t = threadIdx.x;
    int lo = t * per; if (lo > NN) lo = NN;
    int hi = lo + per; if (hi > NN) hi = NN;
    int s = 0;
    for (int i = lo; i < hi; i++) s += cnt[i];
    part[t] = s;
    __syncthreads();
    for (int off = 1; off < T; off <<= 1) {
        int v = (t >= off) ? part[t - off] : 0;
        __syncthreads();
        part[t] += v;
        __syncthreads();
    }
    int run = (t == 0) ? 0 : part[t - 1];
    for (int i = lo; i < hi; i++) { rowptr[i] = run; run += cnt[i]; }
    if (t == T - 1) rowptr[NN] = run;
}

// KSCATTER: place edges into dst-sorted order using precomputed rank.
__global__ void kscatter(const int* __restrict__ src, const int* __restrict__ dst,
                         const int* __restrict__ rowptr, const int* __restrict__ rank,
                         int* __restrict__ srcp, int* __restrict__ dstp) {
    int e = blockIdx.x * blockDim.x + threadIdx.x;
    if (e >= EE) return;
    int d = dst[e];
    int pos = rowptr[d] + rank[e];
    srcp[pos] = src[e];
    dstp[pos] = d;
}

// KXAGG: xagg[n] = sum of x rows over in-edges (CSR gather). wave per node.
__global__ void __launch_bounds__(256) kxagg(const int* __restrict__ rowptr, const int* __restrict__ srcp,
                                             const float* __restrict__ x, float* __restrict__ xagg) {
    int w = (blockIdx.x * blockDim.x + threadIdx.x) >> 6;
    int lane = threadIdx.x & 63;
    if (w >= NN) return;
    int lo = rowptr[w], hi = rowptr[w + 1];
    float acc = 0.f;
    int p = lo;
    for (; p + 3 < hi; p += 4) {
        int s0 = srcp[p], s1 = srcp[p + 1], s2 = srcp[p + 2], s3 = srcp[p + 3];
        float v0 = x[(size_t)s0 * 64 + lane];
        float v1 = x[(size_t)s1 * 64 + lane];
        float v2 = x[(size_t)s2 * 64 + lane];
        float v3 = x[(size_t)s3 * 64 + lane];
        acc += (v0 + v1) + (v2 + v3);
    }
    for (; p < hi; p++) acc += x[(size_t)srcp[p] * 64 + lane];
    xagg[(size_t)w * 64 + lane] = acc;
}

// K3A: thread = (node, j<64). j<32: dagg col j. j>=32: hKagg col (j-32) -> bf16.
//   dagg  = xagg @ WD[:,32:] + cnt*bD[32:]
//   hKagg = xagg[:,32:] @ WencK + cnt*bencK
__global__ void k3a(const float* __restrict__ xagg, const int* __restrict__ cnt,
                    const float* __restrict__ WencK, const float* __restrict__ bencK,
                    const float* __restrict__ WD, const float* __restrict__ bD,
                    float* __restrict__ dagg, __hip_bfloat16* __restrict__ hKaggB) {
    int tid = blockIdx.x * blockDim.x + threadIdx.x;
    int n = tid >> 6;
    int j = tid & 63;
    if (n >= NN) return;
    const float* xa = xagg + (size_t)n * 64;
    float c = (float)cnt[n];
    if (j < 32) {
        float acc = c * bD[32 + j];
        #pragma unroll
        for (int k = 0; k < 64; k++) acc = fmaf(xa[k], WD[k * 64 + 32 + j], acc);
        dagg[(size_t)n * 32 + j] = acc;
    } else {
        int jj = j - 32;
        float acc = c * bencK[jj];
        #pragma unroll
        for (int k = 0; k < 32; k++) acc = fmaf(xa[32 + k], WencK[k * 32 + jj], acc);
        union { __hip_bfloat16 h; short s; } u;
        u.s = f2b(acc);
        hKaggB[(size_t)n * 32 + jj] = u.h;
    }
}

// K3B (MFMA node MLP): wave per 16-node tile, same machinery as k4 but with
// linear loads/stores (consecutive nodes). Enode = mlp3(hKagg) stored bf16.
__global__ void __launch_bounds__(256) k3b(
    const __hip_bfloat16* __restrict__ hKaggB, __hip_bfloat16* __restrict__ EnodeB,
    const float* __restrict__ WK1, const float* __restrict__ bK1,
    const float* __restrict__ WK2, const float* __restrict__ bK2,
    const float* __restrict__ WK3, const float* __restrict__ bK3)
{
    __shared__ float xpose[4][16 * 68];
    const int wid  = threadIdx.x >> 6;
    const int lane = threadIdx.x & 63;
    const int g = lane >> 4;
    const int r = lane & 15;
    float* xp = xpose[wid];

    bf16x8 b1[4];
    #pragma unroll
    for (int nt = 0; nt < 4; nt++) {
        #pragma unroll
        for (int i = 0; i < 8; i++)
            b1[nt][i] = f2b(WK1[(g * 8 + i) * 64 + nt * 16 + r]);
    }
    bf16x8 b2[2][4], b3[2][4];
    #pragma unroll
    for (int c = 0; c < 2; c++) {
        #pragma unroll
        for (int nt = 0; nt < 4; nt++) {
            #pragma unroll
            for (int i = 0; i < 8; i++) {
                b2[c][nt][i] = f2b(WK2[(c * 32 + g * 8 + i) * 64 + nt * 16 + r]);
                b3[c][nt][i] = f2b(WK3[(c * 32 + g * 8 + i) * 64 + nt * 16 + r]);
            }
        }
    }
    float bias1[4], bias2[4], bias3[4];
    #pragma unroll
    for (int nt = 0; nt < 4; nt++) {
        bias1[nt] = bK1[nt * 16 + r];
        bias2[nt] = bK2[nt * 16 + r];
        bias3[nt] = bK3[nt * 16 + r];
    }

    const int ntiles = NN / 16;            // 3125 exact
    const int wave = blockIdx.x * 4 + wid;
    const int nw = gridDim.x * 4;
    const f32x4 zero = {0.f, 0.f, 0.f, 0.f};

    for (int tile = wave; tile < ntiles; tile += nw) {
        // A: node row = tile*16 + r, k = g*8 + i  (16B linear load)
        bf16x8 a;
        {
            uint4 u = *reinterpret_cast<const uint4*>(hKaggB + ((size_t)tile * 16 + r) * 32 + g * 8);
            union { uint4 v; bf16x8 b; } cv; cv.v = u; a = cv.b;
        }
        f32x4 acc[4];
        #pragma unroll
        for (int nt = 0; nt < 4; nt++)
            acc[nt] = __builtin_amdgcn_mfma_f32_16x16x32_bf16(a, b1[nt], zero, 0, 0, 0);

        #pragma unroll
        for (int nt = 0; nt < 4; nt++) {
            #pragma unroll
            for (int q = 0; q < 4; q++)
                xp[(g * 4 + q) * 68 + nt * 16 + r] = fast_tanh(acc[nt][q] + bias1[nt]);
        }

        f32x4 acc2[4] = {zero, zero, zero, zero};
        #pragma unroll
        for (int c = 0; c < 2; c++) {
            const float* row = xp + r * 68 + c * 32 + g * 8;
            bf16x8 af;
            #pragma unroll
            for (int i = 0; i < 8; i++) af[i] = f2b(row[i]);
            #pragma unroll
            for (int nt = 0; nt < 4; nt++)
                acc2[nt] = __builtin_amdgcn_mfma_f32_16x16x32_bf16(af, b2[c][nt], acc2[nt], 0, 0, 0);
        }
        #pragma unroll
        for (int nt = 0; nt < 4; nt++) {
            #pragma unroll
            for (int q = 0; q < 4; q++)
                xp[(g * 4 + q) * 68 + nt * 16 + r] = fmaxf(acc2[nt][q] + bias2[nt], 0.f);
        }

        f32x4 acc3[4] = {zero, zero, zero, zero};
        #pragma unroll
        for (int c = 0; c < 2; c++) {
            const float* row = xp + r * 68 + c * 32 + g * 8;
            bf16x8 af;
            #pragma unroll
            for (int i = 0; i < 8; i++) af[i] = f2b(row[i]);
            #pragma unroll
            for (int nt = 0; nt < 4; nt++)
                acc3[nt] = __builtin_amdgcn_mfma_f32_16x16x32_bf16(af, b3[c][nt], acc3[nt], 0, 0, 0);
        }

        // transpose through LDS, then linear bf16 row-stores (32B per lane)
        #pragma unroll
        for (int nt = 0; nt < 4; nt++) {
            #pragma unroll
            for (int q = 0; q < 4; q++)
                xp[(g * 4 + q) * 68 + nt * 16 + r] = acc3[nt][q] + bias3[nt];
        }
        {
            const float* row = xp + r * 68 + g * 16;
            unsigned int u[8];
            #pragma unroll
            for (int i = 0; i < 8; i++) u[i] = pack2(row[2 * i], row[2 * i + 1]);
            unsigned int* ob = reinterpret_cast<unsigned int*>(EnodeB + ((size_t)tile * 16 + r) * 64 + g * 16);
            uint4 v0 = {u[0], u[1], u[2], u[3]};
            uint4 v1 = {u[4], u[5], u[6], u[7]};
            *reinterpret_cast<uint4*>(ob) = v0;
            *reinterpret_cast<uint4*>(ob + 4) = v1;
        }
    }
}

// K4 v3 (MFMA, row-stream chunks, carry-merged scatter).
__global__ void __launch_bounds__(256) k4_mfma(
    const int* __restrict__ srcp, const int* __restrict__ dstp,
    const __hip_bfloat16* __restrict__ h1b, const __hip_bfloat16* __restrict__ h2b,
    const __hip_bfloat16* __restrict__ EnodeB, float* __restrict__ Enew,
    const float* __restrict__ WU1, const float* __restrict__ bU1,
    const float* __restrict__ WU2, const float* __restrict__ bU2,
    const float* __restrict__ WU3, const float* __restrict__ bU3)
{
    __shared__ float xpose[4][16 * 68];
    const int wid  = threadIdx.x >> 6;
    const int lane = threadIdx.x & 63;
    const int g = lane >> 4;
    const int r = lane & 15;
    float* xp = xpose[wid];

    bf16x8 b1[4];
    #pragma unroll
    for (int nt = 0; nt < 4; nt++) {
        #pragma unroll
        for (int i = 0; i < 8; i++)
            b1[nt][i] = f2b(WU1[(g * 8 + i) * 64 + nt * 16 + r]);
    }
    bf16x8 b2[2][4], b3[2][4];
    #pragma unroll
    for (int c = 0; c < 2; c++) {
        #pragma unroll
        for (int nt = 0; nt < 4; nt++) {
            #pragma unroll
            for (int i = 0; i < 8; i++) {
                b2[c][nt][i] = f2b(WU2[(c * 32 + g * 8 + i) * 64 + nt * 16 + r]);
                b3[c][nt][i] = f2b(WU3[(c * 32 + g * 8 + i) * 64 + nt * 16 + r]);
            }
        }
    }
    float bias1[4], bias2[4], bias3[4];
    #pragma unroll
    for (int nt = 0; nt < 4; nt++) {
        bias1[nt] = bU1[nt * 16 + r];
        bias2[nt] = bU2[nt * 16 + r];
        bias3[nt] = bU3[nt * 16 + r];
    }

    const int wave = blockIdx.x * 4 + wid;     // [0, K4_WAVES)
    const int base = wave * K4_EPW;
    const f32x4 zero = {0.f, 0.f, 0.f, 0.f};

    int   cd[4] = {-1, -1, -1, -1};
    float cv0[4] = {0, 0, 0, 0}, cv1[4] = {0, 0, 0, 0},
          cv2[4] = {0, 0, 0, 0}, cv3[4] = {0, 0, 0, 0};

    for (int t = 0; t < K4_C; t++) {
        const int e_r = base + r * K4_C + t;
        const int s_me = srcp[e_r];
        const int d_me = dstp[e_r];

        bf16x8 a;
        {
            union { uint4 v; unsigned int u[4]; } u1, u2;
            u1.v = *reinterpret_cast<const uint4*>(h1b + (size_t)s_me * 32 + g * 8);
            u2.v = *reinterpret_cast<const uint4*>(h2b + (size_t)d_me * 32 + g * 8);
            #pragma unroll
            for (int w = 0; w < 4; w++) {
                float lo = b2f((unsigned short)(u1.u[w] & 0xffff)) + b2f((unsigned short)(u2.u[w] & 0xffff));
                float hi = b2f((unsigned short)(u1.u[w] >> 16))    + b2f((unsigned short)(u2.u[w] >> 16));
                a[2 * w]     = f2b(lo);
                a[2 * w + 1] = f2b(hi);
            }
        }
        f32x4 acc[4];
        #pragma unroll
        for (int nt = 0; nt < 4; nt++)
            acc[nt] = __builtin_amdgcn_mfma_f32_16x16x32_bf16(a, b1[nt], zero, 0, 0, 0);

        #pragma unroll
        for (int nt = 0; nt < 4; nt++) {
            #pragma unroll
            for (int q = 0; q < 4; q++)
                xp[(g * 4 + q) * 68 + nt * 16 + r] = fast_tanh(acc[nt][q] + bias1[nt]);
        }

        f32x4 acc2[4] = {zero, zero, zero, zero};
        #pragma unroll
        for (int c = 0; c < 2; c++) {
            const float* row = xp + r * 68 + c * 32 + g * 8;
            bf16x8 af;
            #pragma unroll
            for (int i = 0; i < 8; i++) af[i] = f2b(row[i]);
            #pragma unroll
            for (int nt = 0; nt < 4; nt++)
                acc2[nt] = __builtin_amdgcn_mfma_f32_16x16x32_bf16(af, b2[c][nt], acc2[nt], 0, 0, 0);
        }
        #pragma unroll
        for (int nt = 0; nt < 4; nt++) {
            #pragma unroll
            for (int q = 0; q < 4; q++)
                xp[(g * 4 + q) * 68 + nt * 16 + r] = fmaxf(acc2[nt][q] + bias2[nt], 0.f);
        }

        f32x4 acc3[4] = {zero, zero, zero, zero};
        #pragma unroll
        for (int c = 0; c < 2; c++) {
            const float* row = xp + r * 68 + c * 32 + g * 8;
            bf16x8 af;
            #pragma unroll
            for (int i = 0; i < 8; i++) af[i] = f2b(row[i]);
            #pragma unroll
            for (int nt = 0; nt < 4; nt++)
                acc3[nt] = __builtin_amdgcn_mfma_f32_16x16x32_bf16(af, b3[c][nt], acc3[nt], 0, 0, 0);
        }

        #pragma unroll
        for (int q = 0; q < 4; q++) {
            const int er = g * 4 + q;
            const int ssv = __shfl(s_me, er);
            const int dqv = __shfl(d_me, er);
            const unsigned short* enp = reinterpret_cast<const unsigned short*>(EnodeB) + (size_t)ssv * 64 + r;
            float v0 = (acc3[0][q] + bias3[0]) * b2f(enp[0]);
            float v1 = (acc3[1][q] + bias3[1]) * b2f(enp[16]);
            float v2 = (acc3[2][q] + bias3[2]) * b2f(enp[32]);
            float v3 = (acc3[3][q] + bias3[3]) * b2f(enp[48]);
            if (dqv == cd[q]) {
                cv0[q] += v0; cv1[q] += v1; cv2[q] += v2; cv3[q] += v3;
            } else {
                if (cd[q] >= 0) {
                    float* ew = Enew + (size_t)cd[q] * 64 + r;
                    atomAddF(ew,      cv0[q]);
                    atomAddF(ew + 16, cv1[q]);
                    atomAddF(ew + 32, cv2[q]);
                    atomAddF(ew + 48, cv3[q]);
                }
                cd[q] = dqv;
                cv0[q] = v0; cv1[q] = v1; cv2[q] = v2; cv3[q] = v3;
            }
        }
    }
    #pragma unroll
    for (int q = 0; q < 4; q++) {
        if (cd[q] >= 0) {
            float* ew = Enew + (size_t)cd[q] * 64 + r;
            atomAddF(ew,      cv0[q]);
            atomAddF(ew + 16, cv1[q]);
            atomAddF(ew + 32, cv2[q]);
            atomAddF(ew + 48, cv3[q]);
        }
    }
}

// K5: dH = E_new @ WH + bH ; out = [dH[:,32:], -dH[:,:32] - dagg]
__global__ void k5_out(const float* __restrict__ Enew, const float* __restrict__ dagg,
                       const float* __restrict__ WH, const float* __restrict__ bH,
                       float* __restrict__ out) {
    int tid = blockIdx.x * blockDim.x + threadIdx.x;
    int n = tid >> 6;
    int j = tid & 63;
    if (n >= NN) return;
    const float* er = Enew + (size_t)n * 64;
    int jj = (j < 32) ? (j + 32) : (j - 32);
    float acc = bH[jj];
    #pragma unroll
    for (int k = 0; k < 64; k++) acc = fmaf(er[k], WH[k * 64 + jj], acc);
    float val;
    if (j < 32) val = acc;
    else        val = -acc - dagg[(size_t)n * 32 + (j - 32)];
    out[tid] = val;
}

extern "C" void kernel_launch(void* const* d_in, const int* in_sizes, int n_in,
                              void* d_out, int out_size, void* d_ws, size_t ws_size,
                              hipStream_t stream) {
    const float* x      = (const float*)d_in[0];
    const int*   src    = (const int*)d_in[1];
    const int*   dst    = (const int*)d_in[2];
    const float* WencK  = (const float*)d_in[3];
    const float* bencK  = (const float*)d_in[4];
    const float* WencP1 = (const float*)d_in[5];
    const float* bencP1 = (const float*)d_in[6];
    const float* WencP2 = (const float*)d_in[7];
    const float* bencP2 = (const float*)d_in[8];
    const float* WK1    = (const float*)d_in[9];
    const float* bK1    = (const float*)d_in[10];
    const float* WK2    = (const float*)d_in[11];
    const float* bK2    = (const float*)d_in[12];
    const float* WK3    = (const float*)d_in[13];
    const float* bK3    = (const float*)d_in[14];
    const float* WU1    = (const float*)d_in[15];
    const float* bU1    = (const float*)d_in[16];
    const float* WU2    = (const float*)d_in[17];
    const float* bU2    = (const float*)d_in[18];
    const float* WU3    = (const float*)d_in[19];
    const float* bU3    = (const float*)d_in[20];
    const float* WH     = (const float*)d_in[21];
    const float* bH     = (const float*)d_in[22];
    const float* WD     = (const float*)d_in[23];
    const float* bD     = (const float*)d_in[24];
    float* out = (float*)d_out;

    // ---- workspace layout ----
    float* Enew = (float*)d_ws;                                  // NN*64 f32
    float* xagg = Enew + (size_t)NN * 64;                        // NN*64 f32
    float* dagg = xagg + (size_t)NN * 64;                        // NN*32 f32
    __hip_bfloat16* h1b    = (__hip_bfloat16*)(dagg + (size_t)NN * 32);  // NN*32 bf16
    __hip_bfloat16* h2b    = h1b + (size_t)NN * 32;              // NN*32 bf16
    __hip_bfloat16* EnodeB = h2b + (size_t)NN * 32;              // NN*64 bf16
    __hip_bfloat16* hKaggB = EnodeB + (size_t)NN * 64;           // NN*32 bf16
    int* cnt    = (int*)(hKaggB + (size_t)NN * 32);              // NN
    int* rowptr = cnt + NN;                                      // NN+1
    int* rank   = rowptr + NN + 1;                               // EE
    int* srcp   = rank + EE;                                     // EE
    int* dstp   = srcp + EE;                                     // EE
    size_t need = (size_t)NN * 160 * 4 + (size_t)NN * 160 * 2
                + ((size_t)NN * 2 + 1 + (size_t)EE * 3) * 4;
    if (ws_size < need) return;

    hipMemsetAsync(cnt, 0, (size_t)NN * sizeof(int), stream);
    hipMemsetAsync(Enew, 0, (size_t)NN * 64 * sizeof(float), stream);

    khist<<<(EE + 255) / 256, 256, 0, stream>>>(dst, cnt, rank);
    kscan<<<1, 1024, 0, stream>>>(cnt, rowptr);
    kscatter<<<(EE + 255) / 256, 256, 0, stream>>>(src, dst, rowptr, rank, srcp, dstp);
    k1b<<<(NN * 32 + 255) / 256, 256, 0, stream>>>(x, WencP1, bencP1, WencP2, bencP2, h1b, h2b);
    kxagg<<<(NN * 64 + 255) / 256, 256, 0, stream>>>(rowptr, srcp, x, xagg);
    k3a<<<(NN * 64 + 255) / 256, 256, 0, stream>>>(xagg, cnt, WencK, bencK, WD, bD, dagg, hKaggB);
    k3b<<<782, 256, 0, stream>>>(hKaggB, EnodeB, WK1, bK1, WK2, bK2, WK3, bK3);
    k4_mfma<<<K4_WAVES / 4, 256, 0, stream>>>(srcp, dstp, h1b, h2b, EnodeB, Enew,
                                              WU1, bU1, WU2, bU2, WU3, bU3);
    k5_out<<<(NN * 64 + 255) / 256, 256, 0, stream>>>(Enew, dagg, WH, bH, out);
}